// Round 3
// baseline (403.746 us; speedup 1.0000x reference)
//
#include <hip/hip_runtime.h>
#include <cfloat>

// Problem constants (from reference setup_inputs): B=4096, C=10, H=W=30
#define CC     10
#define HWP    900
#define NBATCH 4096
#define NPIX_INV (1.0/3686400.0)   // 1/(B*H*W)

// Workspace: facc[0]=sum(ce*w), facc[1]=sum((changed-t_changed)^2)
//            iacc[0]=count(exact), iacc[1]=count(copy), iacc[2]=sum(missing)
//
// R5: compiler-proof MLP. R1-R4 showed hipcc's allocator rotates ~6 payload
// VGPRs and serializes the 30 loads into dependent batches (VGPR_Count=20,
// ~2.5 loads in flight, 149 us latency-bound) no matter how the source is
// structured -- sched_barrier included. Fix: issue the 30 loads as inline-asm
// global_load_dword with "=v" outputs (asm outputs CANNOT be rotated or
// rematerialized -> 30 results forced live), then one explicit
// s_waitcnt vmcnt(0) + sched_barrier(0) (guide rule #18) before consumption.
// 30 loads x 256 B/wave = 7.5 KB in flight per wave; launch_bounds(1024,8)
// -> VGPR<=64 -> 2 blocks/CU = 32 waves/CU -> ~240 KB in flight per CU.
__global__ __launch_bounds__(1024, 8) void per_sample_kernel(
    const float* __restrict__ pred,
    const float* __restrict__ target,
    const float* __restrict__ grid,
    float* __restrict__ facc,
    unsigned int* __restrict__ iacc)
{
    const int b   = blockIdx.x;
    const int tid = threadIdx.x;
    const size_t base = (size_t)b * (CC * HWP);

    float ce_w_sum = 0.f;
    // packed counts: bits [0:10)=pred!=target, [10:20)=target!=grid, [20:30)=pred!=grid
    unsigned cnts = 0;
    // packed presence masks: bits [0:10)=pred colors, [16:26)=target colors
    unsigned masks = 0;

    if (tid < HWP) {                 // 900 pixels, 1 per thread
        const float* pb = pred   + base + tid;
        const float* tb = target + base + tid;
        const float* gb = grid   + base + tid;

        // ---- issue ALL 30 loads via inline asm (forced-live outputs) ----
        float pv[CC], tv[CC], gv[CC];
        #pragma unroll
        for (int c = 0; c < CC; ++c)
            asm volatile("global_load_dword %0, %1, off"
                         : "=v"(pv[c]) : "v"(pb + c * HWP));
        #pragma unroll
        for (int c = 0; c < CC; ++c)
            asm volatile("global_load_dword %0, %1, off"
                         : "=v"(tv[c]) : "v"(tb + c * HWP));
        #pragma unroll
        for (int c = 0; c < CC; ++c)
            asm volatile("global_load_dword %0, %1, off"
                         : "=v"(gv[c]) : "v"(gb + c * HWP));

        // one wait for all 30, then fence so no consumer hoists above it
        asm volatile("s_waitcnt vmcnt(0)" ::: "memory");
        __builtin_amdgcn_sched_barrier(0);

        // ---- consume from registers (static indices under full unroll) ----
        float pmax = -FLT_MAX, tmax = -FLT_MAX, gmax = -FLT_MAX, pat = 0.f;
        int   pidx = 0, tidx = 0, gidx = 0;
        // pred argmax
        #pragma unroll
        for (int c = 0; c < CC; ++c)
            if (pv[c] > pmax) { pmax = pv[c]; pidx = c; }
        // target argmax + gather pred at target-argmax (static index c)
        #pragma unroll
        for (int c = 0; c < CC; ++c)
            if (tv[c] > tmax) { tmax = tv[c]; tidx = c; pat = pv[c]; }
        // input_grid argmax
        #pragma unroll
        for (int c = 0; c < CC; ++c)
            if (gv[c] > gmax) { gmax = gv[c]; gidx = c; }
        // exp-sum with known max (10 independent exps, no serial rescale chain)
        float esum = 0.f;
        #pragma unroll
        for (int c = 0; c < CC; ++c)
            esum += __expf(pv[c] - pmax);

        const float ce  = pmax + __logf(esum) - pat;   // lse - pred[tidx]
        const unsigned inc = (pidx != tidx);
        ce_w_sum = ce * (1.f + 2.f * (float)inc);
        cnts  = inc
              + ((unsigned)(tidx != gidx) << 10)
              + ((unsigned)(pidx != gidx) << 20);
        masks = (1u << pidx) | (1u << (16 + tidx));
    }

    // wave-64 shuffle reduction (3 values)
    #pragma unroll
    for (int off = 32; off > 0; off >>= 1) {
        ce_w_sum += __shfl_down(ce_w_sum, off);
        cnts     += __shfl_down(cnts, off);
        masks    |= __shfl_down(masks, off);
    }

    __shared__ float    s_ce[16];
    __shared__ unsigned s_cn[16], s_mk[16];
    const int wave = tid >> 6, lane = tid & 63;
    if (lane == 0) { s_ce[wave] = ce_w_sum; s_cn[wave] = cnts; s_mk[wave] = masks; }
    __syncthreads();
    if (tid == 0) {
        float ce = 0.f; unsigned cn = 0, mk = 0;
        #pragma unroll
        for (int w = 0; w < 16; ++w) { ce += s_ce[w]; cn += s_cn[w]; mk |= s_mk[w]; }
        const int pt = cn & 0x3FF, tg = (cn >> 10) & 0x3FF, pg = (cn >> 20) & 0x3FF;
        atomicAdd(&facc[0], ce);
        const float d = (float)(pg - tg) * (1.0f / 900.0f);
        atomicAdd(&facc[1], d * d);
        if (pt == 0)           atomicAdd(&iacc[0], 1u);      // exact match
        if (tg > 0 && pg == 0) atomicAdd(&iacc[1], 1u);      // should_not_copy & did_copy
        const unsigned miss = (mk >> 16) & ~mk & 0x3FFu;
        if (miss)              atomicAdd(&iacc[2], (unsigned)__popc(miss));
    }
}

__global__ void finalize_kernel(const float* __restrict__ facc,
                                const unsigned* __restrict__ iacc,
                                float* __restrict__ out)
{
    if (threadIdx.x == 0 && blockIdx.x == 0) {
        const float ce_mean        = (float)((double)facc[0] * NPIX_INV);
        const float ce_loss        = ce_mean + 0.5f * (float)iacc[2];
        const float exact_bonus    = -10.0f * ((float)iacc[0] / (float)NBATCH);
        const float copy_penalty   =   5.0f * ((float)iacc[1] / (float)NBATCH);
        const float transform_diff = (facc[1] / (float)NBATCH) * 2.0f;
        out[0] = ce_loss + exact_bonus + copy_penalty + transform_diff;
        out[1] = ce_loss;
        out[2] = exact_bonus;
        out[3] = copy_penalty;
        out[4] = transform_diff;
        out[5] = (float)iacc[0];   // jnp.sum(exact)
    }
}

extern "C" void kernel_launch(void* const* d_in, const int* in_sizes, int n_in,
                              void* d_out, int out_size, void* d_ws, size_t ws_size,
                              hipStream_t stream) {
    const float* pred   = (const float*)d_in[0];
    const float* target = (const float*)d_in[1];
    const float* grid   = (const float*)d_in[2];
    float*    out  = (float*)d_out;
    float*    facc = (float*)d_ws;
    unsigned* iacc = (unsigned*)((char*)d_ws + 16);

    hipMemsetAsync(d_ws, 0, 64, stream);
    per_sample_kernel<<<NBATCH, 1024, 0, stream>>>(pred, target, grid, facc, iacc);
    finalize_kernel<<<1, 64, 0, stream>>>(facc, iacc, out);
}

// Round 4
// 402.890 us; speedup vs baseline: 1.0021x; 1.0021x over previous
//
#include <hip/hip_runtime.h>
#include <cfloat>

// Problem constants: B=4096, C=10, H=W=30
#define CC     10
#define HWP    900
#define NBATCH 4096
#define NPIX_INV (1.0/3686400.0)   // 1/(B*H*W)
#define SLAB_B 36000               // bytes per (sample,array) slab = 10*900*4

// R6: DRAM-pattern fix. R3-R5 proved the limit is NOT per-wave MLP (asm-forced
// 30-in-flight loads changed nothing): every pixel-strided variant converges at
// 149 us = 442 MB / 2.97 TB/s. Theory: hundreds of interleaved fine-grained
// strided streams defeat DRAM row locality (~25% HBM efficiency). Fix: make the
// global traffic IDENTICAL to the 6.3 TB/s copy bench -- sequential 16 B/lane
// global_load_lds bursts staging each 36 KB slab into LDS, compute from LDS.
// Double-buffered, counted vmcnt (T3/T4 recipe: raw s_barrier, never drain to 0
// mid-pipeline), 2 blocks/CU (72 KB LDS), ~144 KB in flight per CU.
typedef const __attribute__((address_space(1))) void* gas_p;
typedef __attribute__((address_space(3))) void*       las_p;

__global__ __launch_bounds__(256) void per_sample_kernel(
    const float* __restrict__ pred,
    const float* __restrict__ target,
    const float* __restrict__ grid,
    float* __restrict__ facc,
    unsigned int* __restrict__ iacc)
{
    __shared__ float buf[2][9000];          // 2 x 36000 B
    __shared__ float    s_ce[4];
    __shared__ unsigned s_cn[4], s_mk[4];

    const int b   = blockIdx.x;
    const int tid = threadIdx.x;
    const size_t slab = (size_t)b * SLAB_B; // byte offset of this sample's slab

    // stage one 36000 B slab: 9 rounds x 256 lanes x 16 B (round 8 partial: 202)
    // per-lane lds ptr = base + tid*16 (HW uses firstlane + lane*16 -> linear)
    auto stage = [&](const char* gsrc, char* lbase) {
        #pragma unroll
        for (int i = 0; i < 9; ++i) {
            if (i < 8 || tid < 202) {
                const int off = i * 4096 + tid * 16;
                __builtin_amdgcn_global_load_lds((gas_p)(gsrc + off),
                                                 (las_p)(lbase + off), 16, 0, 0);
            }
        }
    };

    // ---- pipeline: stage T, stage P, [wait T] compute T, stage G,
    //      [wait P] compute P, [wait G] compute G ----
    stage((const char*)target + slab, (char*)&buf[0][0]);
    stage((const char*)pred   + slab, (char*)&buf[1][0]);

    asm volatile("s_waitcnt vmcnt(9)" ::: "memory");   // T done, P in flight
    __builtin_amdgcn_sched_barrier(0);
    __builtin_amdgcn_s_barrier();

    // ---- phase T: target argmax (from buf[0]) ----
    float tmax[4]; int tidx[4];
    if (tid < 225) {
        #pragma unroll
        for (int k = 0; k < 4; ++k) { tmax[k] = -FLT_MAX; tidx[k] = 0; }
        #pragma unroll
        for (int c = 0; c < CC; ++c) {
            const float4 tv = *(const float4*)&buf[0][c * HWP + 4 * tid];
            const float ta[4] = {tv.x, tv.y, tv.z, tv.w};
            #pragma unroll
            for (int k = 0; k < 4; ++k)
                if (ta[k] > tmax[k]) { tmax[k] = ta[k]; tidx[k] = c; }
        }
    }
    __builtin_amdgcn_s_barrier();                      // all done reading buf[0]

    stage((const char*)grid + slab, (char*)&buf[0][0]); // G -> buf[0]

    asm volatile("s_waitcnt vmcnt(9)" ::: "memory");   // P done, G in flight
    __builtin_amdgcn_sched_barrier(0);
    __builtin_amdgcn_s_barrier();

    // ---- phase P: pred argmax, gather at tidx, exp-sum (from buf[1]) ----
    float pmax[4], pat[4], esum[4]; int pidx[4];
    if (tid < 225) {
        #pragma unroll
        for (int k = 0; k < 4; ++k) {
            pmax[k] = -FLT_MAX; pidx[k] = 0; pat[k] = 0.f; esum[k] = 0.f;
        }
        #pragma unroll
        for (int c = 0; c < CC; ++c) {
            const float4 pv = *(const float4*)&buf[1][c * HWP + 4 * tid];
            const float pa[4] = {pv.x, pv.y, pv.z, pv.w};
            #pragma unroll
            for (int k = 0; k < 4; ++k)
                if (pa[k] > pmax[k]) { pmax[k] = pa[k]; pidx[k] = c; }
        }
        #pragma unroll
        for (int k = 0; k < 4; ++k)                    // dynamic gather pv[tidx]
            pat[k] = buf[1][tidx[k] * HWP + 4 * tid + k];
        #pragma unroll
        for (int c = 0; c < CC; ++c) {
            const float4 pv = *(const float4*)&buf[1][c * HWP + 4 * tid];
            const float pa[4] = {pv.x, pv.y, pv.z, pv.w};
            #pragma unroll
            for (int k = 0; k < 4; ++k)
                esum[k] += __expf(pa[k] - pmax[k]);
        }
    }

    asm volatile("s_waitcnt vmcnt(0)" ::: "memory");   // G done
    __builtin_amdgcn_sched_barrier(0);
    __builtin_amdgcn_s_barrier();

    // ---- phase G: input_grid argmax (from buf[0]) + combine ----
    float ce_w_sum = 0.f;
    unsigned cnts = 0, masks = 0;
    if (tid < 225) {
        float gmax[4]; int gidx[4];
        #pragma unroll
        for (int k = 0; k < 4; ++k) { gmax[k] = -FLT_MAX; gidx[k] = 0; }
        #pragma unroll
        for (int c = 0; c < CC; ++c) {
            const float4 gv = *(const float4*)&buf[0][c * HWP + 4 * tid];
            const float ga[4] = {gv.x, gv.y, gv.z, gv.w};
            #pragma unroll
            for (int k = 0; k < 4; ++k)
                if (ga[k] > gmax[k]) { gmax[k] = ga[k]; gidx[k] = c; }
        }
        #pragma unroll
        for (int k = 0; k < 4; ++k) {
            const float ce  = pmax[k] + __logf(esum[k]) - pat[k]; // lse - pred[tidx]
            const unsigned inc = (pidx[k] != tidx[k]);
            ce_w_sum += ce * (1.f + 2.f * (float)inc);
            cnts  += inc
                   + ((unsigned)(tidx[k] != gidx[k]) << 10)
                   + ((unsigned)(pidx[k] != gidx[k]) << 20);
            masks |= (1u << pidx[k]) | (1u << (16 + tidx[k]));
        }
    }

    // wave-64 shuffle reduction (3 values)
    #pragma unroll
    for (int off = 32; off > 0; off >>= 1) {
        ce_w_sum += __shfl_down(ce_w_sum, off);
        cnts     += __shfl_down(cnts, off);
        masks    |= __shfl_down(masks, off);
    }

    const int wave = tid >> 6, lane = tid & 63;
    if (lane == 0) { s_ce[wave] = ce_w_sum; s_cn[wave] = cnts; s_mk[wave] = masks; }
    __syncthreads();
    if (tid == 0) {
        float ce = 0.f; unsigned cn = 0, mk = 0;
        #pragma unroll
        for (int w = 0; w < 4; ++w) { ce += s_ce[w]; cn += s_cn[w]; mk |= s_mk[w]; }
        const int pt = cn & 0x3FF, tg = (cn >> 10) & 0x3FF, pg = (cn >> 20) & 0x3FF;
        atomicAdd(&facc[0], ce);
        const float d = (float)(pg - tg) * (1.0f / 900.0f);
        atomicAdd(&facc[1], d * d);
        if (pt == 0)           atomicAdd(&iacc[0], 1u);      // exact match
        if (tg > 0 && pg == 0) atomicAdd(&iacc[1], 1u);      // should_not_copy & did_copy
        const unsigned miss = (mk >> 16) & ~mk & 0x3FFu;
        if (miss)              atomicAdd(&iacc[2], (unsigned)__popc(miss));
    }
}

__global__ void finalize_kernel(const float* __restrict__ facc,
                                const unsigned* __restrict__ iacc,
                                float* __restrict__ out)
{
    if (threadIdx.x == 0 && blockIdx.x == 0) {
        const float ce_mean        = (float)((double)facc[0] * NPIX_INV);
        const float ce_loss        = ce_mean + 0.5f * (float)iacc[2];
        const float exact_bonus    = -10.0f * ((float)iacc[0] / (float)NBATCH);
        const float copy_penalty   =   5.0f * ((float)iacc[1] / (float)NBATCH);
        const float transform_diff = (facc[1] / (float)NBATCH) * 2.0f;
        out[0] = ce_loss + exact_bonus + copy_penalty + transform_diff;
        out[1] = ce_loss;
        out[2] = exact_bonus;
        out[3] = copy_penalty;
        out[4] = transform_diff;
        out[5] = (float)iacc[0];   // jnp.sum(exact)
    }
}

extern "C" void kernel_launch(void* const* d_in, const int* in_sizes, int n_in,
                              void* d_out, int out_size, void* d_ws, size_t ws_size,
                              hipStream_t stream) {
    const float* pred   = (const float*)d_in[0];
    const float* target = (const float*)d_in[1];
    const float* grid   = (const float*)d_in[2];
    float*    out  = (float*)d_out;
    float*    facc = (float*)d_ws;
    unsigned* iacc = (unsigned*)((char*)d_ws + 16);

    hipMemsetAsync(d_ws, 0, 64, stream);
    per_sample_kernel<<<NBATCH, 256, 0, stream>>>(pred, target, grid, facc, iacc);
    finalize_kernel<<<1, 64, 0, stream>>>(facc, iacc, out);
}